// Round 16
// baseline (127.018 us; speedup 1.0000x reference)
//
#include <hip/hip_runtime.h>
#include <hip/hip_bf16.h>
#include <cstdint>
#include <cstddef>

typedef __bf16 bf16;
typedef __attribute__((ext_vector_type(8))) __bf16 bf16x8;
typedef __attribute__((ext_vector_type(4))) __bf16 bf16x4;
typedef __attribute__((ext_vector_type(4))) float f32x4;
typedef __attribute__((ext_vector_type(16))) float f32x16;
typedef __attribute__((ext_vector_type(4))) unsigned int u32x4;

#define MFMA16x16x32(a, b, c) __builtin_amdgcn_mfma_f32_16x16x32_bf16((a), (b), (c), 0, 0, 0)
#define MFMA32x32x16(a, b, c) __builtin_amdgcn_mfma_f32_32x32x16_bf16((a), (b), (c), 0, 0, 0)

__device__ __forceinline__ void gload16(const void* g, void* l) {
  __builtin_amdgcn_global_load_lds((const __attribute__((address_space(1))) unsigned int*)g,
                                   (__attribute__((address_space(3))) unsigned int*)l,
                                   16, 0, 0);
}

__device__ __forceinline__ unsigned packbf(float a, float b) {
  unsigned short ua = __builtin_bit_cast(unsigned short, (bf16)a);
  unsigned short ub = __builtin_bit_cast(unsigned short, (bf16)b);
  return (unsigned)ua | ((unsigned)ub << 16);
}

// raw v_exp_f32 (2^x): single VOP1 (verified R12/R13). x < -126 -> exact 0.
__device__ __forceinline__ float fexp2(float x) {
  float r;
  asm("v_exp_f32 %0, %1" : "=v"(r) : "v"(x));
  return r;
}

// ============ fused preprocessing: one dispatch, block-range dispatch ============
__global__ __launch_bounds__(256) void prep_fused(const float* __restrict__ x,
                                                  const float* __restrict__ w_c,
                                                  const float* __restrict__ w_k,
                                                  const float* __restrict__ w_v,
                                                  const float* __restrict__ w_q,
                                                  const float* __restrict__ w_o,
                                                  bf16* __restrict__ xb,
                                                  bf16* __restrict__ BTq,
                                                  bf16* __restrict__ WoutT) {
  __shared__ __align__(16) char smem[2 * 64 * 65 * 4];
  const int bi = blockIdx.x;
  const int t = threadIdx.x;

  if (bi < 4096) {  // ---- x convert ----
    int i = bi * 256 + t;
    float4 v = reinterpret_cast<const float4*>(x)[i];
    bf16x4 o;
    o[0] = (bf16)v.x; o[1] = (bf16)v.y; o[2] = (bf16)v.z; o[3] = (bf16)v.w;
    *reinterpret_cast<bf16x4*>(xb + (size_t)i * 4) = o;
    return;
  }

  if (bi < 4112) {  // ---- w_c transpose -> BTq rows 1024..1087 ----
    auto tile = (bf16(*)[72])smem;
    const int r0 = (bi - 4096) * 64;
    bf16* out = BTq + (size_t)1024 * 1024;
    {
      int rr = t >> 4;
      int cc = (t & 15) * 4;
#pragma unroll
      for (int p = 0; p < 4; ++p) {
        float4 v = *(const float4*)&w_c[(size_t)(r0 + rr + 16 * p) * 64 + cc];
        bf16x4 o;
        o[0] = (bf16)v.x; o[1] = (bf16)v.y; o[2] = (bf16)v.z; o[3] = (bf16)v.w;
        *(bf16x4*)&tile[rr + 16 * p][cc] = o;
      }
    }
    __syncthreads();
    {
      int cc = t >> 3;
      int rr = (t & 7) * 8;
#pragma unroll
      for (int p = 0; p < 2; ++p) {
        bf16x8 v;
#pragma unroll
        for (int j = 0; j < 8; ++j) v[j] = tile[rr + j][cc + 32 * p];
        *(bf16x8*)&out[(size_t)(cc + 32 * p) * 1024 + r0 + rr] = v;
      }
    }
    return;
  }

  auto Aq = (float(*)[65])smem;
  auto Ak = (float(*)[65])(smem + 64 * 65 * 4);

  if (bi < 4368) {  // ---- W_qlatT (scale folded) ----
    const int blk = bi - 4112;
    const int h = blk >> 4, dm0 = (blk & 15) * 64;
    {
      int row = t >> 2, c0 = (t & 3) * 16;
#pragma unroll
      for (int j = 0; j < 4; ++j) {
        float4 vq = *(const float4*)&w_q[(size_t)(dm0 + row) * 1024 + h * 64 + c0 + 4 * j];
        Aq[row][c0 + 4 * j + 0] = vq.x; Aq[row][c0 + 4 * j + 1] = vq.y;
        Aq[row][c0 + 4 * j + 2] = vq.z; Aq[row][c0 + 4 * j + 3] = vq.w;
        float4 vk = *(const float4*)&w_k[(size_t)row * 1024 + h * 64 + c0 + 4 * j];
        Ak[row][c0 + 4 * j + 0] = vk.x; Ak[row][c0 + 4 * j + 1] = vk.y;
        Ak[row][c0 + 4 * j + 2] = vk.z; Ak[row][c0 + 4 * j + 3] = vk.w;
      }
    }
    __syncthreads();
    const int ld0 = (t >> 4) * 4, dmq = (t & 15) * 4;
    float acc[4][4] = {};
    for (int dh = 0; dh < 64; ++dh) {
      float rk[4], rq[4];
#pragma unroll
      for (int i = 0; i < 4; ++i) rk[i] = Ak[ld0 + i][dh];
#pragma unroll
      for (int j = 0; j < 4; ++j) rq[j] = Aq[dmq + j][dh];
#pragma unroll
      for (int i = 0; i < 4; ++i)
#pragma unroll
        for (int j = 0; j < 4; ++j) acc[i][j] += rk[i] * rq[j];
    }
    const float S = 0.18033688011112042f;  // 1/sqrt(64) * log2(e)
#pragma unroll
    for (int i = 0; i < 4; ++i) {
      bf16x4 o;
#pragma unroll
      for (int j = 0; j < 4; ++j) o[j] = (bf16)(acc[i][j] * S);
      *(bf16x4*)&BTq[(size_t)(h * 64 + ld0 + i) * 1024 + dm0 + dmq] = o;
    }
    return;
  }

  {  // ---- W_outT ----
    const int blk = bi - 4368;
    const int h = blk >> 4, dn0 = (blk & 15) * 64;
    {
      int row = t >> 2, c0 = (t & 3) * 16;
#pragma unroll
      for (int j = 0; j < 4; ++j) {
        float4 vv = *(const float4*)&w_v[(size_t)row * 1024 + h * 64 + c0 + 4 * j];
        Aq[row][c0 + 4 * j + 0] = vv.x; Aq[row][c0 + 4 * j + 1] = vv.y;
        Aq[row][c0 + 4 * j + 2] = vv.z; Aq[row][c0 + 4 * j + 3] = vv.w;
        float4 vo = *(const float4*)&w_o[(size_t)(h * 64 + row) * 1024 + dn0 + c0 + 4 * j];
        Ak[row][c0 + 4 * j + 0] = vo.x; Ak[row][c0 + 4 * j + 1] = vo.y;
        Ak[row][c0 + 4 * j + 2] = vo.z; Ak[row][c0 + 4 * j + 3] = vo.w;
      }
    }
    __syncthreads();
    const int dnq = (t >> 4) * 4, lv0 = (t & 15) * 4;
    float acc[4][4] = {};
    for (int dh = 0; dh < 64; ++dh) {
      float ro[4], rv[4];
#pragma unroll
      for (int i = 0; i < 4; ++i) ro[i] = Ak[dh][dnq + i];
#pragma unroll
      for (int j = 0; j < 4; ++j) rv[j] = Aq[lv0 + j][dh];
#pragma unroll
      for (int i = 0; i < 4; ++i)
#pragma unroll
        for (int j = 0; j < 4; ++j) acc[i][j] += ro[i] * rv[j];
    }
#pragma unroll
    for (int i = 0; i < 4; ++i) {
      bf16x4 o;
#pragma unroll
      for (int j = 0; j < 4; ++j) o[j] = (bf16)acc[i][j];
      *(bf16x4*)&WoutT[(size_t)(dn0 + dnq + i) * 1024 + h * 64 + lv0] = o;
    }
  }
}

// ------------- latT from fused QL buffer, K-PERMUTED layout (R13-verified) -------------
__global__ __launch_bounds__(256) void make_latT(const bf16* __restrict__ QL,
                                                 bf16* __restrict__ latT) {
  __shared__ __align__(16) bf16 tile[64][72];
  const int r0 = blockIdx.x * 64;
  const int t = threadIdx.x;
  {
    int row = t >> 2, c0 = (t & 3) * 16;
    const bf16* src = QL + (size_t)(r0 + row) * 1088 + 1024 + c0;
    *(bf16x8*)&tile[row][c0] = *(const bf16x8*)src;
    *(bf16x8*)&tile[row][c0 + 8] = *(const bf16x8*)(src + 8);
  }
  __syncthreads();
  {
    int d = t >> 2, tc = (t & 3) * 16;
    const int g1[8] = {0, 1, 2, 3, 8, 9, 10, 11};
    const int g2[8] = {4, 5, 6, 7, 12, 13, 14, 15};
    bf16x8 v0, v1;
#pragma unroll
    for (int j = 0; j < 8; ++j) {
      v0[j] = tile[tc + g1[j]][d];
      v1[j] = tile[tc + g2[j]][d];
    }
    *(bf16x8*)&latT[(size_t)d * 4096 + r0 + tc] = v0;
    *(bf16x8*)&latT[(size_t)d * 4096 + r0 + tc + 8] = v1;
  }
}

// ---------------- bf16 MFMA GEMM: C[M,N] = A[M,K] * BT[N,K]^T (BK templated) ----------------
template <int BM, int BN, int BK, int WM, int WN, bool OUT_F32>
__global__ __launch_bounds__(256) void gemm_bf16(const bf16* __restrict__ A,
                                                 const bf16* __restrict__ BT,
                                                 void* __restrict__ C,
                                                 int N, int K) {
  constexpr int TM = (BM / WM) / 16;
  constexpr int TN = (BN / WN) / 16;
  constexpr int KK = BK / 32;
  constexpr int ROWB = BK * 2;  // bytes per LDS row
  __shared__ __align__(16) bf16 As[BM * BK];
  __shared__ __align__(16) bf16 Bs[BN * BK];
  const int tid = threadIdx.x;
  const int lane = tid & 63;
  const int wid = tid >> 6;
  const int wm = wid / WN;
  const int wn = wid % WN;
  const int bm = blockIdx.x * BM;
  const int bn = blockIdx.y * BN;
  const int arow = lane & 15;
  const int koff = (lane >> 4) * 8;

  f32x4 acc[TM][TN] = {};

  for (int kb = 0; kb < K; kb += BK) {
    for (int base = wid * 1024; base < BM * ROWB; base += 4096) {
      int off = base + lane * 16;
      int row = off / ROWB;
      int col = off % ROWB;
      gload16((const char*)A + ((size_t)(bm + row) * K + kb) * 2 + col, (char*)As + base);
    }
    for (int base = wid * 1024; base < BN * ROWB; base += 4096) {
      int off = base + lane * 16;
      int row = off / ROWB;
      int col = off % ROWB;
      gload16((const char*)BT + ((size_t)(bn + row) * K + kb) * 2 + col, (char*)Bs + base);
    }
    __syncthreads();

    bf16x8 af[TM][KK], bfr[TN][KK];
#pragma unroll
    for (int i = 0; i < TM; ++i)
#pragma unroll
      for (int kk = 0; kk < KK; ++kk)
        af[i][kk] = *(const bf16x8*)&As[(wm * TM * 16 + i * 16 + arow) * BK + kk * 32 + koff];
#pragma unroll
    for (int j = 0; j < TN; ++j)
#pragma unroll
      for (int kk = 0; kk < KK; ++kk)
        bfr[j][kk] = *(const bf16x8*)&Bs[(wn * TN * 16 + j * 16 + arow) * BK + kk * 32 + koff];
#pragma unroll
    for (int i = 0; i < TM; ++i)
#pragma unroll
      for (int j = 0; j < TN; ++j)
#pragma unroll
        for (int kk = 0; kk < KK; ++kk)
          acc[i][j] = MFMA16x16x32(af[i][kk], bfr[j][kk], acc[i][j]);
    __syncthreads();
  }

  const int m0 = bm + wm * TM * 16 + (lane >> 4) * 4;
  const int n0 = bn + wn * TN * 16 + (lane & 15);
#pragma unroll
  for (int i = 0; i < TM; ++i)
#pragma unroll
    for (int j = 0; j < TN; ++j)
#pragma unroll
      for (int r = 0; r < 4; ++r) {
        int m = m0 + i * 16 + r;
        int n = n0 + j * 16;
        float v = acc[i][j][r];
        if constexpr (OUT_F32)
          ((float*)C)[(size_t)m * N + n] = v;
        else
          ((bf16*)C)[(size_t)m * N + n] = (bf16)v;
      }
}

// ---------------- absorbed flash attention v13: shared K/V, 4-deep ring, 1 barrier/tile ----------------
// R15 structure (block = chunk x b x head-group of 4; cooperative gload_lds K/V)
// with a 4-buffer ring and ONE barrier per tile. Safety: single barrier/iter
// bounds inter-wave skew to 1 iteration; stage at iter t writes buf[(t+2)&3],
// laggiest reader is on buf[(t-1)&3] -- distance 3 mod 4, no alias. Each wave
// drains its OWN staged loads (vmcnt) before the barrier, so post-barrier all
// contributions are visible (R2/R15-verified invariant). vmcnt: steady 4
// (2 tiles x 2 loads in flight), tail 2 then 0.
__global__ __launch_bounds__(256) void mla_attn5(const bf16* __restrict__ QL,
                                                 const bf16* __restrict__ latT,
                                                 bf16* __restrict__ out_lat) {
  __shared__ __align__(16) bf16 Kst[4][2048];      // [buf][32 tok][128B rows], swizzled
  __shared__ __align__(16) bf16 Vst[4][2048];      // [buf][32 srows][128B], swizzled
  __shared__ __align__(16) bf16 etile[4][32][72];  // per-wave output transpose
  const int tid = threadIdx.x, lane = tid & 63, w = tid >> 6;
  const int c_raw = blockIdx.x & 63;
  const int rest = (int)(blockIdx.x >> 6);         // 0..7
  const int b = rest & 1;
  const int hg = (rest >> 1) & 3;
  const int c = (rest < 4) ? (63 - c_raw) : c_raw; // complementary pairing
  const int h = hg * 4 + w;                        // this wave's head
  const int nt = c + 1;
  const int q0 = c * 32;
  const int li = lane & 31;
  const int hb = lane >> 5;
  const size_t boff = (size_t)b * 2048;
  const bf16* lat = QL + 1024;  // latent columns (row stride 1088)

  const int drow = tid >> 3;
  const int dbyte = (tid & 7) * 16;
  const int sbyte = dbyte ^ ((drow & 7) << 4);  // inverse swizzle (involution)
  const int vd = 2 * drow + (sbyte >> 6);
  const int vkof = (sbyte & 63) >> 1;
  auto stage = [&](int buf, int kb) {
    gload16((const char*)lat + ((size_t)(boff + kb + drow) * 1088) * 2 + sbyte,
            (char*)&Kst[buf][0] + w * 1024);
    gload16((const char*)latT + ((size_t)vd * 4096 + boff + kb + vkof) * 2,
            (char*)&Vst[buf][0] + w * 1024);
  };

  bf16x8 qf[4];
  {
    const bf16* qp = QL + ((size_t)(boff + q0 + li)) * 1088 + h * 64 + hb * 8;
#pragma unroll
    for (int s = 0; s < 4; ++s) qf[s] = *(const bf16x8*)(qp + 16 * s);
  }

  float lsum = 0.f;
  f32x16 ot0 = {}, ot1 = {};

  stage(0, 0);
  if (nt > 1) stage(1, 32);
  for (int t = 0; t < nt; ++t) {
    const int cur = t & 3;
    if (t + 2 < nt) {
      stage((t + 2) & 3, (t + 2) * 32);
      asm volatile("s_waitcnt vmcnt(4)" ::: "memory");  // own S_t drained; S_{t+1},S_{t+2} in flight
    } else if (t + 1 < nt) {
      asm volatile("s_waitcnt vmcnt(2)" ::: "memory");
    } else {
      asm volatile("s_waitcnt vmcnt(0)" ::: "memory");
    }
    __builtin_amdgcn_s_barrier();
    __builtin_amdgcn_sched_barrier(0);

    // ---- swizzled LDS reads ----
    bf16x8 ka[4], va[2][2];
#pragma unroll
    for (int s = 0; s < 4; ++s)
      ka[s] = *(const bf16x8*)((const char*)&Kst[cur][0] + li * 128 +
                               ((hb * 16 + 32 * s) ^ ((li & 7) << 4)));
#pragma unroll
    for (int ldb = 0; ldb < 2; ++ldb) {
      const int srow = 16 * ldb + (li >> 1);
#pragma unroll
      for (int s2 = 0; s2 < 2; ++s2) {
        const int vb = (li & 1) * 64 + hb * 16 + 32 * s2;
        va[ldb][s2] = *(const bf16x8*)((const char*)&Vst[cur][0] + srow * 128 +
                                       (vb ^ ((srow & 7) << 4)));
      }
    }

    // ---- tile compute (R13-verbatim) ----
    f32x16 st = {};
    __builtin_amdgcn_s_setprio(1);
#pragma unroll
    for (int s = 0; s < 4; ++s) st = MFMA32x32x16(ka[s], qf[s], st);
    __builtin_amdgcn_s_setprio(0);
    if (t == nt - 1) {  // diagonal tile: k_local > q_local
#pragma unroll
      for (int r = 0; r < 16; ++r) {
        const int krow = (r & 3) + 8 * (r >> 2) + 4 * hb;
        if (krow > li) st[r] = -30000.f;
      }
    }
    float pv[16];
#pragma unroll
    for (int r = 0; r < 16; ++r) {
      pv[r] = fexp2(st[r]);
      lsum += pv[r];
    }
    u32x4 w1, w2;
    w1[0] = packbf(pv[0], pv[1]);  w1[1] = packbf(pv[2], pv[3]);
    w1[2] = packbf(pv[4], pv[5]);  w1[3] = packbf(pv[6], pv[7]);
    w2[0] = packbf(pv[8], pv[9]);  w2[1] = packbf(pv[10], pv[11]);
    w2[2] = packbf(pv[12], pv[13]); w2[3] = packbf(pv[14], pv[15]);
    const bf16x8 pb1 = __builtin_bit_cast(bf16x8, w1);
    const bf16x8 pb2 = __builtin_bit_cast(bf16x8, w2);
    __builtin_amdgcn_s_setprio(1);
    ot0 = MFMA32x32x16(va[0][0], pb1, ot0);
    ot0 = MFMA32x32x16(va[0][1], pb2, ot0);
    ot1 = MFMA32x32x16(va[1][0], pb1, ot1);
    ot1 = MFMA32x32x16(va[1][1], pb2, ot1);
    __builtin_amdgcn_s_setprio(0);
  }

  lsum += __shfl_xor(lsum, 32);  // merge the two half-row k-sets

  // epilogue: O^T regs -> per-wave LDS transpose -> coalesced store
  const float inv = 1.0f / lsum;
#pragma unroll
  for (int r = 0; r < 16; ++r) {
    const int ldr = (r & 3) + 8 * (r >> 2) + 4 * hb;
    etile[w][li][ldr] = (bf16)(ot0[r] * inv);
    etile[w][li][ldr + 32] = (bf16)(ot1[r] * inv);
  }
  asm volatile("s_waitcnt lgkmcnt(0)" ::: "memory");
  __builtin_amdgcn_sched_barrier(0);
  {
    bf16* op = out_lat + ((size_t)(boff + q0 + li)) * 1024 + h * 64 + hb * 32;
#pragma unroll
    for (int j = 0; j < 4; ++j)
      *(bf16x8*)(op + 8 * j) = *(const bf16x8*)&etile[w][li][hb * 32 + 8 * j];
  }
}

// ---------------- host launch ----------------
extern "C" void kernel_launch(void* const* d_in, const int* in_sizes, int n_in,
                              void* d_out, int out_size, void* d_ws, size_t ws_size,
                              hipStream_t stream) {
  const float* x   = (const float*)d_in[0];
  const float* w_c = (const float*)d_in[1];
  const float* w_k = (const float*)d_in[2];
  const float* w_v = (const float*)d_in[3];
  const float* w_q = (const float*)d_in[4];
  const float* w_o = (const float*)d_in[5];
  float* out = (float*)d_out;

  char* ws = (char*)d_ws;
  size_t off = 0;
  auto alloc = [&](size_t bytes) {
    char* p = ws + off;
    off += (bytes + 255) & ~(size_t)255;
    return p;
  };
  bf16* xb     = (bf16*)alloc((size_t)4096 * 1024 * 2);
  bf16* QLbuf  = (bf16*)alloc((size_t)4096 * 1088 * 2);  // q_lat | latent
  bf16* BTq    = (bf16*)alloc((size_t)1088 * 1024 * 2);  // W_qlatT ; w_c^T
  bf16* latT   = (bf16*)alloc((size_t)64 * 4096 * 2);
  bf16* outlat = (bf16*)alloc((size_t)4096 * 1024 * 2);
  bf16* WoutT  = (bf16*)alloc((size_t)1024 * 1024 * 2);

  // 1) all preprocessing in one dispatch
  prep_fused<<<4624, 256, 0, stream>>>(x, w_c, w_k, w_v, w_q, w_o, xb, BTq, WoutT);

  // 2) fused [q_lat | latent] = xb @ [W_qlatT ; w_c^T]^T : [4096][1088], BK=64
  gemm_bf16<128, 64, 64, 2, 2, false><<<dim3(32, 17), 256, 0, stream>>>(
      xb, BTq, QLbuf, 1088, 1024);

  // 3) latT [64][4096] (k-permuted) from QLbuf latent columns
  make_latT<<<64, 256, 0, stream>>>(QLbuf, latT);

  // 4) attention: 512 blocks = (64 chunks x 2 b x 4 head-groups), 4 waves/block
  mla_attn5<<<512, 256, 0, stream>>>(QLbuf, latT, outlat);

  // 5) out = out_lat @ W_outT (fp32), BK=64
  gemm_bf16<64, 128, 64, 1, 4, true><<<dim3(64, 8), 256, 0, stream>>>(
      outlat, WoutT, (void*)out, 1024, 1024);

  (void)in_sizes; (void)n_in; (void)out_size; (void)ws_size;
}

// Round 17
// 103.784 us; speedup vs baseline: 1.2239x; 1.2239x over previous
//
#include <hip/hip_runtime.h>
#include <hip/hip_bf16.h>
#include <cstdint>
#include <cstddef>

typedef __bf16 bf16;
typedef __attribute__((ext_vector_type(8))) __bf16 bf16x8;
typedef __attribute__((ext_vector_type(4))) __bf16 bf16x4;
typedef __attribute__((ext_vector_type(4))) float f32x4;
typedef __attribute__((ext_vector_type(16))) float f32x16;
typedef __attribute__((ext_vector_type(4))) unsigned int u32x4;

#define MFMA16x16x32(a, b, c) __builtin_amdgcn_mfma_f32_16x16x32_bf16((a), (b), (c), 0, 0, 0)
#define MFMA32x32x16(a, b, c) __builtin_amdgcn_mfma_f32_32x32x16_bf16((a), (b), (c), 0, 0, 0)

__device__ __forceinline__ void gload16(const void* g, void* l) {
  __builtin_amdgcn_global_load_lds((const __attribute__((address_space(1))) unsigned int*)g,
                                   (__attribute__((address_space(3))) unsigned int*)l,
                                   16, 0, 0);
}

__device__ __forceinline__ unsigned packbf(float a, float b) {
  unsigned short ua = __builtin_bit_cast(unsigned short, (bf16)a);
  unsigned short ub = __builtin_bit_cast(unsigned short, (bf16)b);
  return (unsigned)ua | ((unsigned)ub << 16);
}

// raw v_exp_f32 (2^x): single VOP1 (verified R12/R13). x < -126 -> exact 0.
__device__ __forceinline__ float fexp2(float x) {
  float r;
  asm("v_exp_f32 %0, %1" : "=v"(r) : "v"(x));
  return r;
}

// ============ fused preprocessing: one dispatch, block-range dispatch ============
__global__ __launch_bounds__(256) void prep_fused(const float* __restrict__ x,
                                                  const float* __restrict__ w_c,
                                                  const float* __restrict__ w_k,
                                                  const float* __restrict__ w_v,
                                                  const float* __restrict__ w_q,
                                                  const float* __restrict__ w_o,
                                                  bf16* __restrict__ xb,
                                                  bf16* __restrict__ BTq,
                                                  bf16* __restrict__ WoutT) {
  __shared__ __align__(16) char smem[2 * 64 * 65 * 4];
  const int bi = blockIdx.x;
  const int t = threadIdx.x;

  if (bi < 4096) {  // ---- x convert ----
    int i = bi * 256 + t;
    float4 v = reinterpret_cast<const float4*>(x)[i];
    bf16x4 o;
    o[0] = (bf16)v.x; o[1] = (bf16)v.y; o[2] = (bf16)v.z; o[3] = (bf16)v.w;
    *reinterpret_cast<bf16x4*>(xb + (size_t)i * 4) = o;
    return;
  }

  if (bi < 4112) {  // ---- w_c transpose -> BTq rows 1024..1087 ----
    auto tile = (bf16(*)[72])smem;
    const int r0 = (bi - 4096) * 64;
    bf16* out = BTq + (size_t)1024 * 1024;
    {
      int rr = t >> 4;
      int cc = (t & 15) * 4;
#pragma unroll
      for (int p = 0; p < 4; ++p) {
        float4 v = *(const float4*)&w_c[(size_t)(r0 + rr + 16 * p) * 64 + cc];
        bf16x4 o;
        o[0] = (bf16)v.x; o[1] = (bf16)v.y; o[2] = (bf16)v.z; o[3] = (bf16)v.w;
        *(bf16x4*)&tile[rr + 16 * p][cc] = o;
      }
    }
    __syncthreads();
    {
      int cc = t >> 3;
      int rr = (t & 7) * 8;
#pragma unroll
      for (int p = 0; p < 2; ++p) {
        bf16x8 v;
#pragma unroll
        for (int j = 0; j < 8; ++j) v[j] = tile[rr + j][cc + 32 * p];
        *(bf16x8*)&out[(size_t)(cc + 32 * p) * 1024 + r0 + rr] = v;
      }
    }
    return;
  }

  auto Aq = (float(*)[65])smem;
  auto Ak = (float(*)[65])(smem + 64 * 65 * 4);

  if (bi < 4368) {  // ---- W_qlatT (scale folded) ----
    const int blk = bi - 4112;
    const int h = blk >> 4, dm0 = (blk & 15) * 64;
    {
      int row = t >> 2, c0 = (t & 3) * 16;
#pragma unroll
      for (int j = 0; j < 4; ++j) {
        float4 vq = *(const float4*)&w_q[(size_t)(dm0 + row) * 1024 + h * 64 + c0 + 4 * j];
        Aq[row][c0 + 4 * j + 0] = vq.x; Aq[row][c0 + 4 * j + 1] = vq.y;
        Aq[row][c0 + 4 * j + 2] = vq.z; Aq[row][c0 + 4 * j + 3] = vq.w;
        float4 vk = *(const float4*)&w_k[(size_t)row * 1024 + h * 64 + c0 + 4 * j];
        Ak[row][c0 + 4 * j + 0] = vk.x; Ak[row][c0 + 4 * j + 1] = vk.y;
        Ak[row][c0 + 4 * j + 2] = vk.z; Ak[row][c0 + 4 * j + 3] = vk.w;
      }
    }
    __syncthreads();
    const int ld0 = (t >> 4) * 4, dmq = (t & 15) * 4;
    float acc[4][4] = {};
    for (int dh = 0; dh < 64; ++dh) {
      float rk[4], rq[4];
#pragma unroll
      for (int i = 0; i < 4; ++i) rk[i] = Ak[ld0 + i][dh];
#pragma unroll
      for (int j = 0; j < 4; ++j) rq[j] = Aq[dmq + j][dh];
#pragma unroll
      for (int i = 0; i < 4; ++i)
#pragma unroll
        for (int j = 0; j < 4; ++j) acc[i][j] += rk[i] * rq[j];
    }
    const float S = 0.18033688011112042f;  // 1/sqrt(64) * log2(e)
#pragma unroll
    for (int i = 0; i < 4; ++i) {
      bf16x4 o;
#pragma unroll
      for (int j = 0; j < 4; ++j) o[j] = (bf16)(acc[i][j] * S);
      *(bf16x4*)&BTq[(size_t)(h * 64 + ld0 + i) * 1024 + dm0 + dmq] = o;
    }
    return;
  }

  {  // ---- W_outT ----
    const int blk = bi - 4368;
    const int h = blk >> 4, dn0 = (blk & 15) * 64;
    {
      int row = t >> 2, c0 = (t & 3) * 16;
#pragma unroll
      for (int j = 0; j < 4; ++j) {
        float4 vv = *(const float4*)&w_v[(size_t)row * 1024 + h * 64 + c0 + 4 * j];
        Aq[row][c0 + 4 * j + 0] = vv.x; Aq[row][c0 + 4 * j + 1] = vv.y;
        Aq[row][c0 + 4 * j + 2] = vv.z; Aq[row][c0 + 4 * j + 3] = vv.w;
        float4 vo = *(const float4*)&w_o[(size_t)(h * 64 + row) * 1024 + dn0 + c0 + 4 * j];
        Ak[row][c0 + 4 * j + 0] = vo.x; Ak[row][c0 + 4 * j + 1] = vo.y;
        Ak[row][c0 + 4 * j + 2] = vo.z; Ak[row][c0 + 4 * j + 3] = vo.w;
      }
    }
    __syncthreads();
    const int dnq = (t >> 4) * 4, lv0 = (t & 15) * 4;
    float acc[4][4] = {};
    for (int dh = 0; dh < 64; ++dh) {
      float ro[4], rv[4];
#pragma unroll
      for (int i = 0; i < 4; ++i) ro[i] = Ak[dh][dnq + i];
#pragma unroll
      for (int j = 0; j < 4; ++j) rv[j] = Aq[lv0 + j][dh];
#pragma unroll
      for (int i = 0; i < 4; ++i)
#pragma unroll
        for (int j = 0; j < 4; ++j) acc[i][j] += ro[i] * rv[j];
    }
#pragma unroll
    for (int i = 0; i < 4; ++i) {
      bf16x4 o;
#pragma unroll
      for (int j = 0; j < 4; ++j) o[j] = (bf16)acc[i][j];
      *(bf16x4*)&WoutT[(size_t)(dn0 + dnq + i) * 1024 + h * 64 + lv0] = o;
    }
  }
}

// ------------- latT from fused QL buffer, K-PERMUTED layout (R13-verified) -------------
__global__ __launch_bounds__(256) void make_latT(const bf16* __restrict__ QL,
                                                 bf16* __restrict__ latT) {
  __shared__ __align__(16) bf16 tile[64][72];
  const int r0 = blockIdx.x * 64;
  const int t = threadIdx.x;
  {
    int row = t >> 2, c0 = (t & 3) * 16;
    const bf16* src = QL + (size_t)(r0 + row) * 1088 + 1024 + c0;
    *(bf16x8*)&tile[row][c0] = *(const bf16x8*)src;
    *(bf16x8*)&tile[row][c0 + 8] = *(const bf16x8*)(src + 8);
  }
  __syncthreads();
  {
    int d = t >> 2, tc = (t & 3) * 16;
    const int g1[8] = {0, 1, 2, 3, 8, 9, 10, 11};
    const int g2[8] = {4, 5, 6, 7, 12, 13, 14, 15};
    bf16x8 v0, v1;
#pragma unroll
    for (int j = 0; j < 8; ++j) {
      v0[j] = tile[tc + g1[j]][d];
      v1[j] = tile[tc + g2[j]][d];
    }
    *(bf16x8*)&latT[(size_t)d * 4096 + r0 + tc] = v0;
    *(bf16x8*)&latT[(size_t)d * 4096 + r0 + tc + 8] = v1;
  }
}

// ------- bf16 MFMA GEMM: C[M,N] = A[M,K] * BT[N,K]^T, 3-ring prefetch, 1 barrier/step -------
template <int BM, int BN, int WM, int WN, bool OUT_F32>
__global__ __launch_bounds__(256) void gemm_bf16(const bf16* __restrict__ A,
                                                 const bf16* __restrict__ BT,
                                                 void* __restrict__ C,
                                                 int N, int K) {
  constexpr int BK = 32;
  constexpr int TM = (BM / WM) / 16;
  constexpr int TN = (BN / WN) / 16;
  static_assert((BM + BN) * BK * 2 / 4096 == 3, "vmcnt literal assumes 3 loads/thread");
  __shared__ __align__(16) bf16 As[3][BM * BK];
  __shared__ __align__(16) bf16 Bs[3][BN * BK];
  const int tid = threadIdx.x;
  const int lane = tid & 63;
  const int wid = tid >> 6;
  const int wm = wid / WN;
  const int wn = wid % WN;
  const int bm = blockIdx.x * BM;
  const int bn = blockIdx.y * BN;
  const int arow = lane & 15;
  const int koff = (lane >> 4) * 8;

  auto stageg = [&](int buf, int kb) {
    for (int base = wid * 1024; base < BM * 64; base += 4096) {
      int off = base + lane * 16;
      int row = off >> 6;
      int col = off & 63;
      gload16((const char*)A + ((size_t)(bm + row) * K + kb) * 2 + col,
              (char*)&As[buf][0] + base);
    }
    for (int base = wid * 1024; base < BN * 64; base += 4096) {
      int off = base + lane * 16;
      int row = off >> 6;
      int col = off & 63;
      gload16((const char*)BT + ((size_t)(bn + row) * K + kb) * 2 + col,
              (char*)&Bs[buf][0] + base);
    }
  };

  f32x4 acc[TM][TN] = {};
  const int nkt = K / BK;
  stageg(0, 0);
  for (int t = 0; t < nkt; ++t) {
    const int cur = t % 3;
    if (t + 1 < nkt) {
      stageg((t + 1) % 3, (t + 1) * BK);
      asm volatile("s_waitcnt vmcnt(3)" ::: "memory");  // own S_t drained; S_{t+1} in flight
    } else {
      asm volatile("s_waitcnt vmcnt(0)" ::: "memory");
    }
    __builtin_amdgcn_s_barrier();
    __builtin_amdgcn_sched_barrier(0);

    bf16x8 af[TM], bfr[TN];
#pragma unroll
    for (int i = 0; i < TM; ++i)
      af[i] = *(const bf16x8*)&As[cur][(wm * TM * 16 + i * 16 + arow) * BK + koff];
#pragma unroll
    for (int j = 0; j < TN; ++j)
      bfr[j] = *(const bf16x8*)&Bs[cur][(wn * TN * 16 + j * 16 + arow) * BK + koff];
#pragma unroll
    for (int i = 0; i < TM; ++i)
#pragma unroll
      for (int j = 0; j < TN; ++j)
        acc[i][j] = MFMA16x16x32(af[i], bfr[j], acc[i][j]);
  }

  const int m0 = bm + wm * TM * 16 + (lane >> 4) * 4;
  const int n0 = bn + wn * TN * 16 + (lane & 15);
#pragma unroll
  for (int i = 0; i < TM; ++i)
#pragma unroll
    for (int j = 0; j < TN; ++j)
#pragma unroll
      for (int r = 0; r < 4; ++r) {
        int m = m0 + i * 16 + r;
        int n = n0 + j * 16;
        float v = acc[i][j][r];
        if constexpr (OUT_F32)
          ((float*)C)[(size_t)m * N + n] = v;
        else
          ((bf16*)C)[(size_t)m * N + n] = (bf16)v;
      }
}

// ---------------- absorbed flash attention v14: KB=64, 3-ring, 1 barrier/tile ----------------
// R16 structure with 64-token K/V tiles: halves barrier+drain count per token.
// Ring of 3 bufs, prefetch depth 1: stage(t+1) writes buf (t+1)%3; laggiest
// reader (skew <= 1 iter with a single barrier) holds buf (t-1)%3 -- distance 2
// mod 3, no alias. Each wave drains its own 4 staged loads (vmcnt(4)) before its
// barrier (R15/R16-verified invariant). QK split st0/st1 per 32-k half; diagonal
// mask on st0 (c even) or st1 (c odd); c-even last tile skips the all-masked st1.
__global__ __launch_bounds__(256) void mla_attn6(const bf16* __restrict__ QL,
                                                 const bf16* __restrict__ latT,
                                                 bf16* __restrict__ out_lat) {
  __shared__ __align__(16) bf16 Kst[3][4096];      // [buf][64 tok][128B], swizzled
  __shared__ __align__(16) bf16 Vst[3][4096];      // [buf][64 d][128B(64 tok)], swizzled
  __shared__ __align__(16) bf16 etile[4][32][72];  // per-wave output transpose
  const int tid = threadIdx.x, lane = tid & 63, w = tid >> 6;
  const int c_raw = blockIdx.x & 63;
  const int rest = (int)(blockIdx.x >> 6);         // 0..7
  const int b = rest & 1;
  const int hg = (rest >> 1) & 3;
  const int c = (rest < 4) ? (63 - c_raw) : c_raw; // complementary pairing
  const int h = hg * 4 + w;                        // this wave's head
  const int nt = (c + 2) >> 1;                     // 64-token tiles
  const bool ceven = !(c & 1);
  const int q0 = c * 32;
  const int li = lane & 31;
  const int hb = lane >> 5;
  const size_t boff = (size_t)b * 2048;
  const bf16* lat = QL + 1024;  // latent columns (row stride 1088)

  const int r0i = tid >> 3;              // 0..31 (row covered by this thread, per issue)
  const int dby = (tid & 7) * 16;        // byte within 128B row
  auto stage = [&](int buf, int kb) {
#pragma unroll
    for (int i = 0; i < 2; ++i) {
      const int krow = r0i + 32 * i;
      const int sb = dby ^ ((krow & 7) << 4);  // inverse swizzle (involution)
      gload16((const char*)lat + ((size_t)(boff + kb + krow) * 1088) * 2 + sb,
              (char*)&Kst[buf][0] + i * 4096 + w * 1024);
    }
#pragma unroll
    for (int i = 0; i < 2; ++i) {
      const int vrow = r0i + 32 * i;  // d index
      const int sb = dby ^ ((vrow & 7) << 4);
      gload16((const char*)latT + ((size_t)vrow * 4096 + boff + kb) * 2 + sb,
              (char*)&Vst[buf][0] + i * 4096 + w * 1024);
    }
  };

  bf16x8 qf[4];
  {
    const bf16* qp = QL + ((size_t)(boff + q0 + li)) * 1088 + h * 64 + hb * 8;
#pragma unroll
    for (int s = 0; s < 4; ++s) qf[s] = *(const bf16x8*)(qp + 16 * s);
  }

  float lsum = 0.f;
  f32x16 ot0 = {}, ot1 = {};

  stage(0, 0);
  for (int t = 0; t < nt; ++t) {
    const int cur = t % 3;
    if (t + 1 < nt) {
      stage((t + 1) % 3, (t + 1) * 64);
      asm volatile("s_waitcnt vmcnt(4)" ::: "memory");  // own S_t drained; S_{t+1} in flight
    } else {
      asm volatile("s_waitcnt vmcnt(0)" ::: "memory");
    }
    __builtin_amdgcn_s_barrier();
    __builtin_amdgcn_sched_barrier(0);

    const bool last = (t == nt - 1);
    const bool skip1 = last && ceven;  // st1 half fully masked -> skip

    // ---- swizzled LDS reads ----
    bf16x8 ka0[4], ka1[4], va[2][4];
#pragma unroll
    for (int s = 0; s < 4; ++s) {
      const int xo = (hb * 16 + 32 * s) ^ ((li & 7) << 4);
      ka0[s] = *(const bf16x8*)((const char*)&Kst[cur][0] + li * 128 + xo);
      ka1[s] = *(const bf16x8*)((const char*)&Kst[cur][0] + (32 + li) * 128 + xo);
    }
#pragma unroll
    for (int ldb = 0; ldb < 2; ++ldb) {
      const int vrow = 32 * ldb + li;
#pragma unroll
      for (int s2 = 0; s2 < 4; ++s2) {
        const int vb = (32 * s2 + 16 * hb) ^ ((li & 7) << 4);
        va[ldb][s2] = *(const bf16x8*)((const char*)&Vst[cur][0] + vrow * 128 + vb);
      }
    }

    // ---- QK^T ----
    f32x16 st0 = {}, st1 = {};
    __builtin_amdgcn_s_setprio(1);
#pragma unroll
    for (int s = 0; s < 4; ++s) st0 = MFMA32x32x16(ka0[s], qf[s], st0);
    if (!skip1) {
#pragma unroll
      for (int s = 0; s < 4; ++s) st1 = MFMA32x32x16(ka1[s], qf[s], st1);
    }
    __builtin_amdgcn_s_setprio(0);
    if (last) {
#pragma unroll
      for (int r = 0; r < 16; ++r) {
        const int krow = (r & 3) + 8 * (r >> 2) + 4 * hb;
        if (ceven) {
          if (krow > li) st0[r] = -30000.f;
        } else {
          if (krow > li) st1[r] = -30000.f;
        }
      }
    }

    float pv0[16], pv1[16];
#pragma unroll
    for (int r = 0; r < 16; ++r) {
      pv0[r] = fexp2(st0[r]);
      lsum += pv0[r];
    }
    if (!skip1) {
#pragma unroll
      for (int r = 0; r < 16; ++r) {
        pv1[r] = fexp2(st1[r]);
        lsum += pv1[r];
      }
    }

    // shuffle-free P^T fragments (k-permutation aligns crow with B-frag slots)
    u32x4 w1, w2;
    w1[0] = packbf(pv0[0], pv0[1]);   w1[1] = packbf(pv0[2], pv0[3]);
    w1[2] = packbf(pv0[4], pv0[5]);   w1[3] = packbf(pv0[6], pv0[7]);
    w2[0] = packbf(pv0[8], pv0[9]);   w2[1] = packbf(pv0[10], pv0[11]);
    w2[2] = packbf(pv0[12], pv0[13]); w2[3] = packbf(pv0[14], pv0[15]);
    const bf16x8 pb1 = __builtin_bit_cast(bf16x8, w1);
    const bf16x8 pb2 = __builtin_bit_cast(bf16x8, w2);
    __builtin_amdgcn_s_setprio(1);
    ot0 = MFMA32x32x16(va[0][0], pb1, ot0);
    ot0 = MFMA32x32x16(va[0][1], pb2, ot0);
    ot1 = MFMA32x32x16(va[1][0], pb1, ot1);
    ot1 = MFMA32x32x16(va[1][1], pb2, ot1);
    __builtin_amdgcn_s_setprio(0);
    if (!skip1) {
      u32x4 w3, w4;
      w3[0] = packbf(pv1[0], pv1[1]);   w3[1] = packbf(pv1[2], pv1[3]);
      w3[2] = packbf(pv1[4], pv1[5]);   w3[3] = packbf(pv1[6], pv1[7]);
      w4[0] = packbf(pv1[8], pv1[9]);   w4[1] = packbf(pv1[10], pv1[11]);
      w4[2] = packbf(pv1[12], pv1[13]); w4[3] = packbf(pv1[14], pv1[15]);
      const bf16x8 pb3 = __builtin_bit_cast(bf16x8, w3);
      const bf16x8 pb4 = __builtin_bit_cast(bf16x8, w4);
      __builtin_amdgcn_s_setprio(1);
      ot0 = MFMA32x32x16(va[0][2], pb3, ot0);
      ot0 = MFMA32x32x16(va[0][3], pb4, ot0);
      ot1 = MFMA32x32x16(va[1][2], pb3, ot1);
      ot1 = MFMA32x32x16(va[1][3], pb4, ot1);
      __builtin_amdgcn_s_setprio(0);
    }
  }

  lsum += __shfl_xor(lsum, 32);  // merge the two half-row k-sets

  // epilogue: O^T regs -> per-wave LDS transpose -> coalesced store
  const float inv = 1.0f / lsum;
#pragma unroll
  for (int r = 0; r < 16; ++r) {
    const int ldr = (r & 3) + 8 * (r >> 2) + 4 * hb;
    etile[w][li][ldr] = (bf16)(ot0[r] * inv);
    etile[w][li][ldr + 32] = (bf16)(ot1[r] * inv);
  }
  asm volatile("s_waitcnt lgkmcnt(0)" ::: "memory");
  __builtin_amdgcn_sched_barrier(0);
  {
    bf16* op = out_lat + ((size_t)(boff + q0 + li)) * 1024 + h * 64 + hb * 32;
#pragma unroll
    for (int j = 0; j < 4; ++j)
      *(bf16x8*)(op + 8 * j) = *(const bf16x8*)&etile[w][li][hb * 32 + 8 * j];
  }
}

// ---------------- host launch ----------------
extern "C" void kernel_launch(void* const* d_in, const int* in_sizes, int n_in,
                              void* d_out, int out_size, void* d_ws, size_t ws_size,
                              hipStream_t stream) {
  const float* x   = (const float*)d_in[0];
  const float* w_c = (const float*)d_in[1];
  const float* w_k = (const float*)d_in[2];
  const float* w_v = (const float*)d_in[3];
  const float* w_q = (const float*)d_in[4];
  const float* w_o = (const float*)d_in[5];
  float* out = (float*)d_out;

  char* ws = (char*)d_ws;
  size_t off = 0;
  auto alloc = [&](size_t bytes) {
    char* p = ws + off;
    off += (bytes + 255) & ~(size_t)255;
    return p;
  };
  bf16* xb     = (bf16*)alloc((size_t)4096 * 1024 * 2);
  bf16* QLbuf  = (bf16*)alloc((size_t)4096 * 1088 * 2);  // q_lat | latent
  bf16* BTq    = (bf16*)alloc((size_t)1088 * 1024 * 2);  // W_qlatT ; w_c^T
  bf16* latT   = (bf16*)alloc((size_t)64 * 4096 * 2);
  bf16* outlat = (bf16*)alloc((size_t)4096 * 1024 * 2);
  bf16* WoutT  = (bf16*)alloc((size_t)1024 * 1024 * 2);

  // 1) all preprocessing in one dispatch
  prep_fused<<<4624, 256, 0, stream>>>(x, w_c, w_k, w_v, w_q, w_o, xb, BTq, WoutT);

  // 2) fused [q_lat | latent] = xb @ [W_qlatT ; w_c^T]^T : [4096][1088]
  gemm_bf16<128, 64, 2, 2, false><<<dim3(32, 17), 256, 0, stream>>>(
      xb, BTq, QLbuf, 1088, 1024);

  // 3) latT [64][4096] (k-permuted) from QLbuf latent columns
  make_latT<<<64, 256, 0, stream>>>(QLbuf, latT);

  // 4) attention: 512 blocks = (64 chunks x 2 b x 4 head-groups), 4 waves/block
  mla_attn6<<<512, 256, 0, stream>>>(QLbuf, latT, outlat);

  // 5) out = out_lat @ W_outT (fp32)
  gemm_bf16<64, 128, 1, 4, true><<<dim3(64, 8), 256, 0, stream>>>(
      outlat, WoutT, (void*)out, 1024, 1024);

  (void)in_sizes; (void)n_in; (void)out_size; (void)ws_size;
}